// Round 10
// baseline (135.911 us; speedup 1.0000x reference)
//
#include <hip/hip_runtime.h>
#include <stdint.h>

// TrajectoryFK: L=65536, J=22, fp32 in/out.
// R10: ONE kernel. R9 ledger: ~60 us fixed harness reset; controllable ~37 us
// split across K1 (redundant scan) + launch gap + K2. This round folds K1
// into K2's z=0 waves (scan computed ONCE), hands aggregates across blocks
// via spin-flags (R7-validated mechanism, now on the 16-wave/CU shape),
// and needs no flag-memset: harness poisons ws to 0xAA each launch, we spin
// until MAGIC != poison.
// Block dim3(64,4,4): x=lane/t-offset, y=chain, z=quarter. 256 blocks.
// Barriers: 3, reached unconditionally by all 16 waves. Spin only on
// predecessor flags (block b waits for blocks < b; block 0 never spins).

#define LTOT 65536
#define ROW 132                 // 22 joints * 6 floats per timestep (528 B)
#define P1B 256                 // timesteps per block
#define NSCB (LTOT / P1B)       // 256 blocks
#define MAGIC 0x13579BDF

struct Aff { float A[9]; float b[3]; };

__device__ __forceinline__ void d6_to_mat(float a0, float a1, float a2,
                                          float a3, float a4, float a5,
                                          float R[9]) {
  // Gram-Schmidt; columns of R are b1,b2,b3 (row-major R[r*3+c]).
  float n1 = sqrtf(a0 * a0 + a1 * a1 + a2 * a2);
  float i1 = 1.0f / fmaxf(n1, 1e-12f);
  float b10 = a0 * i1, b11 = a1 * i1, b12 = a2 * i1;
  float d = b10 * a3 + b11 * a4 + b12 * a5;
  float c0 = a3 - d * b10, c1 = a4 - d * b11, c2 = a5 - d * b12;
  float n2 = sqrtf(c0 * c0 + c1 * c1 + c2 * c2);
  float i2 = 1.0f / fmaxf(n2, 1e-12f);
  float b20 = c0 * i2, b21 = c1 * i2, b22 = c2 * i2;
  float b30 = b11 * b22 - b12 * b21;
  float b31 = b12 * b20 - b10 * b22;
  float b32 = b10 * b21 - b11 * b20;
  R[0] = b10; R[1] = b20; R[2] = b30;
  R[3] = b11; R[4] = b21; R[5] = b31;
  R[6] = b12; R[7] = b22; R[8] = b32;
}

__device__ __forceinline__ void mat_mul(const float A[9], const float B[9], float C[9]) {
#pragma unroll
  for (int i = 0; i < 3; ++i)
#pragma unroll
    for (int j = 0; j < 3; ++j)
      C[i * 3 + j] = A[i * 3 + 0] * B[0 + j] + A[i * 3 + 1] * B[3 + j] + A[i * 3 + 2] * B[6 + j];
}

__device__ __forceinline__ void mat_vec(const float A[9], float x, float y, float z,
                                        float& ox, float& oy, float& oz) {
  ox = A[0] * x + A[1] * y + A[2] * z;
  oy = A[3] * x + A[4] * y + A[5] * z;
  oz = A[6] * x + A[7] * y + A[8] * z;
}

__device__ __forceinline__ void compose(const Aff& P, const Aff& T, Aff& O) {
  mat_mul(P.A, T.A, O.A);
  float bx, by, bz;
  mat_vec(P.A, T.b[0], T.b[1], T.b[2], bx, by, bz);
  O.b[0] = P.b[0] + bx; O.b[1] = P.b[1] + by; O.b[2] = P.b[2] + bz;
}

__device__ __forceinline__ void aff_identity(Aff& v) {
  v.A[0] = 1.f; v.A[1] = 0.f; v.A[2] = 0.f;
  v.A[3] = 0.f; v.A[4] = 1.f; v.A[5] = 0.f;
  v.A[6] = 0.f; v.A[7] = 0.f; v.A[8] = 1.f;
  v.b[0] = 0.f; v.b[1] = 0.f; v.b[2] = 0.f;
}

__device__ __forceinline__ void wave_scan(Aff& v, int lane) {
#pragma unroll
  for (int s = 1; s < 64; s <<= 1) {
    Aff u;
#pragma unroll
    for (int k = 0; k < 9; ++k) u.A[k] = __shfl_up(v.A[k], s, 64);
#pragma unroll
    for (int k = 0; k < 3; ++k) u.b[k] = __shfl_up(v.b[k], s, 64);
    if (lane >= s) { Aff t; compose(u, v, t); v = t; }
  }
}

__device__ __forceinline__ void elem_transform(const float* __restrict__ pred,
                                               int t, Aff& v) {
  const float4* q4 = (const float4*)(pred + (size_t)t * ROW);  // 16B-aligned
  float4 qa = q4[0];   // j0: v0 v1 v2 .
  float4 qb = q4[1];   // . . e0 e1
  float4 qc = q4[2];   // e2 e3 e4 e5
  d6_to_mat(qb.z, qb.w, qc.x, qc.y, qc.z, qc.w, v.A);          // d_t
  mat_vec(v.A, qa.x, qa.y, qa.z, v.b[0], v.b[1], v.b[2]);      // d_t @ v_t
}

struct Rowv { float2 a, b, c; };
__device__ __forceinline__ Rowv loadrow(const float* q, int j) {
  const float2* p = (const float2*)(q + j * 6);   // 8B-aligned
  Rowv r; r.a = p[0]; r.b = p[1]; r.c = p[2]; return r;
}
__device__ __forceinline__ void rowmat(const Rowv& r, float M[9]) {
  d6_to_mat(r.a.x, r.a.y, r.b.x, r.b.y, r.c.x, r.c.y, M);
}
__device__ __forceinline__ void childp(const float* Rp, const float* offs, int j,
                                       float px, float py, float pz,
                                       float& ox, float& oy, float& oz,
                                       float* ob) {
  float dx, dy, dz;
  mat_vec(Rp, offs[j * 3], offs[j * 3 + 1], offs[j * 3 + 2], dx, dy, dz);
  ox = px + dx; oy = py + dy; oz = pz + dz;
  ob[j * 3] = ox; ob[j * 3 + 1] = oy; ob[j * 3 + 2] = oz;
}

__global__ __launch_bounds__(1024) void fk_fused(const float* __restrict__ pred,
                                                 const float* __restrict__ offs,
                                                 float* __restrict__ agg,
                                                 int* __restrict__ flags,
                                                 float* __restrict__ out) {
  int x = threadIdx.x;            // lane = t offset within quarter
  int y = threadIdx.y;            // chain 0..3 (wave-uniform)
  int z = threadIdx.z;            // quarter 0..3 (wave-uniform)
  int b = blockIdx.x;

  __shared__ float sagg1[4][12];
  __shared__ float sagg2[4][12];
  __shared__ float ebuf[12];
  __shared__ float sg[P1B][13];   // block-local prefix f per t; stride-13 pad

  int tl = z * 64 + x;            // t offset in this block's 256
  int t = b * P1B + tl;
  int s = x + 64 * y;             // scan index 0..255 within the z-group
  const float* q = pred + (size_t)t * ROW;
  float* ob = out + (size_t)t * 66;

  // ---- issue chain row loads FIRST (latency hides under the scan) ----
  Rowv w0, w1, w2, w3, w4, w5, w6, w7, w8;
  if (y == 0) {                    // chain 0: M4, M7
    w0 = loadrow(q, 4); w1 = loadrow(q, 7);
  } else if (y == 1) {             // chain 1: M2, M5, M8
    w0 = loadrow(q, 2); w1 = loadrow(q, 5); w2 = loadrow(q, 8);
  } else if (y == 2) {             // chain 2: M3, M6, M9, M12
    w0 = loadrow(q, 3); w1 = loadrow(q, 6); w2 = loadrow(q, 9);
    w3 = loadrow(q, 12);
  } else {                         // chain 3: prefix M3,M6,M9 + both forks
    w0 = loadrow(q, 3); w1 = loadrow(q, 6); w2 = loadrow(q, 9);
    w3 = loadrow(q, 13); w4 = loadrow(q, 16); w5 = loadrow(q, 18);
    w6 = loadrow(q, 14); w7 = loadrow(q, 17); w8 = loadrow(q, 19);
  }

  // ---- z=0: block-local scan (the ONLY copy of this work) ----
  Aff v;
  if (z == 0) {
    elem_transform(pred, b * P1B + s, v);
    wave_scan(v, x);
    if (x == 63) {
#pragma unroll
      for (int k = 0; k < 9; ++k) sagg1[y][k] = v.A[k];
#pragma unroll
      for (int k = 0; k < 3; ++k) sagg1[y][9 + k] = v.b[k];
    }
  }
  __syncthreads();                               // barrier #1

  Aff v2;                          // z=1's aggregate element
  if (z == 0) {
    Aff pre; aff_identity(pre);
    for (int w = 0; w < y; ++w) {
      Aff gg, t2;
#pragma unroll
      for (int k = 0; k < 9; ++k) gg.A[k] = sagg1[w][k];
#pragma unroll
      for (int k = 0; k < 3; ++k) gg.b[k] = sagg1[w][9 + k];
      compose(pre, gg, t2); pre = t2;
    }
    Aff f; compose(pre, v, f);     // block-local inclusive prefix for t_s
#pragma unroll
    for (int k = 0; k < 9; ++k) sg[s][k] = f.A[k];
#pragma unroll
    for (int k = 0; k < 3; ++k) sg[s][9 + k] = f.b[k];
    if (s == P1B - 1) {            // publish block aggregate + release flag
      float4* a = (float4*)(agg + (size_t)b * 12);
      a[0] = make_float4(f.A[0], f.A[1], f.A[2], f.A[3]);
      a[1] = make_float4(f.A[4], f.A[5], f.A[6], f.A[7]);
      a[2] = make_float4(f.A[8], f.b[0], f.b[1], f.b[2]);
      __threadfence();
      __hip_atomic_store(&flags[b], MAGIC, __ATOMIC_RELEASE,
                         __HIP_MEMORY_SCOPE_AGENT);
    }
  } else if (z == 1) {
    // spin only on PREDECESSOR flags; lanes s>=b contribute identity
    if (s < b) {
      while (__hip_atomic_load(&flags[s], __ATOMIC_ACQUIRE,
                               __HIP_MEMORY_SCOPE_AGENT) != MAGIC) {
        __builtin_amdgcn_s_sleep(1);
      }
      const float4* a = (const float4*)(agg + (size_t)s * 12);
      float4 a0 = a[0], a1 = a[1], a2 = a[2];
      v2.A[0] = a0.x; v2.A[1] = a0.y; v2.A[2] = a0.z; v2.A[3] = a0.w;
      v2.A[4] = a1.x; v2.A[5] = a1.y; v2.A[6] = a1.z; v2.A[7] = a1.w;
      v2.A[8] = a2.x; v2.b[0] = a2.y; v2.b[1] = a2.z; v2.b[2] = a2.w;
    } else {
      aff_identity(v2);
    }
    wave_scan(v2, x);
    if (x == 63) {
#pragma unroll
      for (int k = 0; k < 9; ++k) sagg2[y][k] = v2.A[k];
#pragma unroll
      for (int k = 0; k < 3; ++k) sagg2[y][9 + k] = v2.b[k];
    }
  }
  __syncthreads();                               // barrier #2

  if (z == 1 && b > 0 && s == b - 1) {
    Aff pre; aff_identity(pre);
    for (int w = 0; w < y; ++w) {
      Aff gg, t2;
#pragma unroll
      for (int k = 0; k < 9; ++k) gg.A[k] = sagg2[w][k];
#pragma unroll
      for (int k = 0; k < 3; ++k) gg.b[k] = sagg2[w][9 + k];
      compose(pre, gg, t2); pre = t2;
    }
    Aff incl; compose(pre, v2, incl);   // inclusive agg scan at s = b-1
#pragma unroll
    for (int k = 0; k < 9; ++k) ebuf[k] = incl.A[k];
#pragma unroll
    for (int k = 0; k < 3; ++k) ebuf[9 + k] = incl.b[k];
  }
  __syncthreads();                               // barrier #3

  // ---- per-thread: g = excl-block-prefix ∘ f(tl), then the chain tree ----
  Aff eb;
  if (b == 0) aff_identity(eb);
  else {
#pragma unroll
    for (int k = 0; k < 9; ++k) eb.A[k] = ebuf[k];
#pragma unroll
    for (int k = 0; k < 3; ++k) eb.b[k] = ebuf[9 + k];
  }
  Aff fl;
#pragma unroll
  for (int k = 0; k < 9; ++k) fl.A[k] = sg[tl][k];
#pragma unroll
  for (int k = 0; k < 3; ++k) fl.b[k] = sg[tl][9 + k];
  Aff g; compose(eb, fl, g);
  const float* R = g.A;
  float px = g.b[0], py = g.b[1], pz = g.b[2];

  float M[9], ra[9], rb[9];
  if (y == 0) {                    // stores 0,1,4,7,10
    ob[0] = px; ob[1] = py; ob[2] = pz;
    float p1x, p1y, p1z, p4x, p4y, p4z, p7x, p7y, p7z, dx, dy, dz;
    childp(R, offs, 1, px, py, pz, p1x, p1y, p1z, ob);     // rots[1]=R
    childp(R, offs, 4, p1x, p1y, p1z, p4x, p4y, p4z, ob);  // parent 1, rot R
    rowmat(w0, M); mat_mul(R, M, ra);                      // r4
    childp(ra, offs, 7, p4x, p4y, p4z, p7x, p7y, p7z, ob);
    rowmat(w1, M); mat_mul(ra, M, rb);                     // r7
    childp(rb, offs, 10, p7x, p7y, p7z, dx, dy, dz, ob);
  } else if (y == 1) {             // stores 2,5,8,11
    float p2x, p2y, p2z, p5x, p5y, p5z, p8x, p8y, p8z, dx, dy, dz;
    childp(R, offs, 2, px, py, pz, p2x, p2y, p2z, ob);
    rowmat(w0, M); mat_mul(R, M, ra);                      // r2
    childp(ra, offs, 5, p2x, p2y, p2z, p5x, p5y, p5z, ob);
    rowmat(w1, M); mat_mul(ra, M, rb);                     // r5
    childp(rb, offs, 8, p5x, p5y, p5z, p8x, p8y, p8z, ob);
    rowmat(w2, M); mat_mul(rb, M, ra);                     // r8
    childp(ra, offs, 11, p8x, p8y, p8z, dx, dy, dz, ob);
  } else if (y == 2) {             // stores 3,6,9,12,15
    float p3x, p3y, p3z, p6x, p6y, p6z, p9x, p9y, p9z;
    float p12x, p12y, p12z, dx, dy, dz;
    childp(R, offs, 3, px, py, pz, p3x, p3y, p3z, ob);
    rowmat(w0, M); mat_mul(R, M, ra);                      // r3
    childp(ra, offs, 6, p3x, p3y, p3z, p6x, p6y, p6z, ob);
    rowmat(w1, M); mat_mul(ra, M, rb);                     // r6
    childp(rb, offs, 9, p6x, p6y, p6z, p9x, p9y, p9z, ob);
    rowmat(w2, M); mat_mul(rb, M, ra);                     // r9
    childp(ra, offs, 12, p9x, p9y, p9z, p12x, p12y, p12z, ob);
    rowmat(w3, M); mat_mul(ra, M, rb);                     // r12
    childp(rb, offs, 15, p12x, p12y, p12z, dx, dy, dz, ob);
  } else {                         // stores 13,16,18,20 and 14,17,19,21
    float p3x, p3y, p3z, p6x, p6y, p6z, p9x, p9y, p9z, dx, dy, dz;
    mat_vec(R, offs[9], offs[10], offs[11], dx, dy, dz);
    p3x = px + dx; p3y = py + dy; p3z = pz + dz;
    rowmat(w0, M); mat_mul(R, M, ra);                      // r3
    mat_vec(ra, offs[18], offs[19], offs[20], dx, dy, dz);
    p6x = p3x + dx; p6y = p3y + dy; p6z = p3z + dz;
    rowmat(w1, M); mat_mul(ra, M, rb);                     // r6
    mat_vec(rb, offs[27], offs[28], offs[29], dx, dy, dz);
    p9x = p6x + dx; p9y = p6y + dy; p9z = p6z + dz;
    rowmat(w2, M); mat_mul(rb, M, ra);                     // r9
    float r9s[9];
#pragma unroll
    for (int k = 0; k < 9; ++k) r9s[k] = ra[k];
    float pAx, pAy, pAz, pBx, pBy, pBz, pCx, pCy, pCz;
    childp(r9s, offs, 13, p9x, p9y, p9z, pAx, pAy, pAz, ob);
    rowmat(w3, M); mat_mul(r9s, M, rb);                    // r13
    childp(rb, offs, 16, pAx, pAy, pAz, pBx, pBy, pBz, ob);
    rowmat(w4, M); mat_mul(rb, M, ra);                     // r16
    childp(ra, offs, 18, pBx, pBy, pBz, pCx, pCy, pCz, ob);
    rowmat(w5, M); mat_mul(ra, M, rb);                     // r18
    childp(rb, offs, 20, pCx, pCy, pCz, dx, dy, dz, ob);
    childp(r9s, offs, 14, p9x, p9y, p9z, pAx, pAy, pAz, ob);
    rowmat(w6, M); mat_mul(r9s, M, rb);                    // r14
    childp(rb, offs, 17, pAx, pAy, pAz, pBx, pBy, pBz, ob);
    rowmat(w7, M); mat_mul(rb, M, ra);                     // r17
    childp(ra, offs, 19, pBx, pBy, pBz, pCx, pCy, pCz, ob);
    rowmat(w8, M); mat_mul(ra, M, rb);                     // r19
    childp(rb, offs, 21, pCx, pCy, pCz, dx, dy, dz, ob);
  }
}

extern "C" void kernel_launch(void* const* d_in, const int* in_sizes, int n_in,
                              void* d_out, int out_size, void* d_ws, size_t ws_size,
                              hipStream_t stream) {
  const float* pred = (const float*)d_in[0];   // (L, 22, 6) fp32
  const float* offs = (const float*)d_in[1];   // (22, 3)    fp32
  float* out = (float*)d_out;                  // (L, 22, 3) fp32
  float* agg = (float*)d_ws;                   // 12 * NSCB floats
  int* flags = (int*)((char*)d_ws + 16384);    // 256 ints (0xAA-poisoned;
                                               // we spin for MAGIC, no memset)

  fk_fused<<<NSCB, dim3(64, 4, 4), 0, stream>>>(pred, offs, agg, flags, out);
}

// Round 11
// 97.067 us; speedup vs baseline: 1.4002x; 1.4002x over previous
//
#include <hip/hip_runtime.h>
#include <stdint.h>

// TrajectoryFK: L=65536, J=22, fp32 in/out.
// R11: back to the validated 2-plain-launch structure (R9) — every in-kernel
// cross-block sync variant (R5 coop 57us, R7 flags 61us, R10 flags+16wave
// 82us) lost to it. R10's counters showed the real K2 problem: WRITE_SIZE
// 33.7MB (2x output) + VGPR=64 => chain-3's 9-row preload SPILLED to
// scratch. Fix: rebalanced chains (<=3 live rows/thread), r9/p9 handed from
// chain2 to the fork chains via LDS (+1 barrier), loads on-demand.
//   y0: {0,1,4,7,10} then fork-B {14,17,19,21}
//   y1: {2,5,8,11}   y2: {3,6,9,12,15}+publish r9   y3: fork-A {13,16,18,20}

#define LTOT 65536
#define ROW 132                 // 22 joints * 6 floats per timestep (528 B)
#define P1B 256                 // timesteps per scan block
#define NSCB (LTOT / P1B)       // 256 scan blocks

struct Aff { float A[9]; float b[3]; };

__device__ __forceinline__ void d6_to_mat(float a0, float a1, float a2,
                                          float a3, float a4, float a5,
                                          float R[9]) {
  // Gram-Schmidt; columns of R are b1,b2,b3 (row-major R[r*3+c]).
  float n1 = sqrtf(a0 * a0 + a1 * a1 + a2 * a2);
  float i1 = 1.0f / fmaxf(n1, 1e-12f);
  float b10 = a0 * i1, b11 = a1 * i1, b12 = a2 * i1;
  float d = b10 * a3 + b11 * a4 + b12 * a5;
  float c0 = a3 - d * b10, c1 = a4 - d * b11, c2 = a5 - d * b12;
  float n2 = sqrtf(c0 * c0 + c1 * c1 + c2 * c2);
  float i2 = 1.0f / fmaxf(n2, 1e-12f);
  float b20 = c0 * i2, b21 = c1 * i2, b22 = c2 * i2;
  float b30 = b11 * b22 - b12 * b21;
  float b31 = b12 * b20 - b10 * b22;
  float b32 = b10 * b21 - b11 * b20;
  R[0] = b10; R[1] = b20; R[2] = b30;
  R[3] = b11; R[4] = b21; R[5] = b31;
  R[6] = b12; R[7] = b22; R[8] = b32;
}

__device__ __forceinline__ void mat_mul(const float A[9], const float B[9], float C[9]) {
#pragma unroll
  for (int i = 0; i < 3; ++i)
#pragma unroll
    for (int j = 0; j < 3; ++j)
      C[i * 3 + j] = A[i * 3 + 0] * B[0 + j] + A[i * 3 + 1] * B[3 + j] + A[i * 3 + 2] * B[6 + j];
}

__device__ __forceinline__ void mat_vec(const float A[9], float x, float y, float z,
                                        float& ox, float& oy, float& oz) {
  ox = A[0] * x + A[1] * y + A[2] * z;
  oy = A[3] * x + A[4] * y + A[5] * z;
  oz = A[6] * x + A[7] * y + A[8] * z;
}

__device__ __forceinline__ void compose(const Aff& P, const Aff& T, Aff& O) {
  mat_mul(P.A, T.A, O.A);
  float bx, by, bz;
  mat_vec(P.A, T.b[0], T.b[1], T.b[2], bx, by, bz);
  O.b[0] = P.b[0] + bx; O.b[1] = P.b[1] + by; O.b[2] = P.b[2] + bz;
}

__device__ __forceinline__ void aff_identity(Aff& v) {
  v.A[0] = 1.f; v.A[1] = 0.f; v.A[2] = 0.f;
  v.A[3] = 0.f; v.A[4] = 1.f; v.A[5] = 0.f;
  v.A[6] = 0.f; v.A[7] = 0.f; v.A[8] = 1.f;
  v.b[0] = 0.f; v.b[1] = 0.f; v.b[2] = 0.f;
}

__device__ __forceinline__ void wave_scan(Aff& v, int lane) {
#pragma unroll
  for (int s = 1; s < 64; s <<= 1) {
    Aff u;
#pragma unroll
    for (int k = 0; k < 9; ++k) u.A[k] = __shfl_up(v.A[k], s, 64);
#pragma unroll
    for (int k = 0; k < 3; ++k) u.b[k] = __shfl_up(v.b[k], s, 64);
    if (lane >= s) { Aff t; compose(u, v, t); v = t; }
  }
}

__device__ __forceinline__ void elem_transform(const float* __restrict__ pred,
                                               int t, Aff& v) {
  const float4* q4 = (const float4*)(pred + (size_t)t * ROW);  // 16B-aligned
  float4 qa = q4[0];   // j0: v0 v1 v2 .
  float4 qb = q4[1];   // . . e0 e1
  float4 qc = q4[2];   // e2 e3 e4 e5
  d6_to_mat(qb.z, qb.w, qc.x, qc.y, qc.z, qc.w, v.A);          // d_t
  mat_vec(v.A, qa.x, qa.y, qa.z, v.b[0], v.b[1], v.b[2]);      // d_t @ v_t
}

// ---------------- K1: 256 block aggregates only (R6/R9-validated) --------
__global__ __launch_bounds__(P1B) void fk_agg(const float* __restrict__ pred,
                                              float* __restrict__ agg) {
  int tid = threadIdx.x;
  int t = blockIdx.x * P1B + tid;
  int lane = tid & 63, wid = tid >> 6;
  Aff v;
  elem_transform(pred, t, v);
  wave_scan(v, lane);
  __shared__ float sagg[P1B / 64][12];
  if (lane == 63) {
#pragma unroll
    for (int k = 0; k < 9; ++k) sagg[wid][k] = v.A[k];
#pragma unroll
    for (int k = 0; k < 3; ++k) sagg[wid][9 + k] = v.b[k];
  }
  __syncthreads();
  if (tid == P1B - 1) {
    Aff pre; aff_identity(pre);
    for (int w = 0; w < P1B / 64 - 1; ++w) {
      Aff g, t2;
#pragma unroll
      for (int k = 0; k < 9; ++k) g.A[k] = sagg[w][k];
#pragma unroll
      for (int k = 0; k < 3; ++k) g.b[k] = sagg[w][9 + k];
      compose(pre, g, t2); pre = t2;
    }
    Aff f; compose(pre, v, f);
    float4* a = (float4*)(agg + (size_t)blockIdx.x * 12);
    a[0] = make_float4(f.A[0], f.A[1], f.A[2], f.A[3]);
    a[1] = make_float4(f.A[4], f.A[5], f.A[6], f.A[7]);
    a[2] = make_float4(f.A[8], f.b[0], f.b[1], f.b[2]);
  }
}

// ---------------- K2: scan + rebalanced spill-free tree ------------------
struct Rowv { float2 a, b, c; };
__device__ __forceinline__ Rowv loadrow(const float* q, int j) {
  const float2* p = (const float2*)(q + j * 6);   // 8B-aligned
  Rowv r; r.a = p[0]; r.b = p[1]; r.c = p[2]; return r;
}
__device__ __forceinline__ void rowmat(const Rowv& r, float M[9]) {
  d6_to_mat(r.a.x, r.a.y, r.b.x, r.b.y, r.c.x, r.c.y, M);
}
__device__ __forceinline__ void childp(const float* Rp, const float* offs, int j,
                                       float px, float py, float pz,
                                       float& ox, float& oy, float& oz,
                                       float* ob) {
  float dx, dy, dz;
  mat_vec(Rp, offs[j * 3], offs[j * 3 + 1], offs[j * 3 + 2], dx, dy, dz);
  ox = px + dx; oy = py + dy; oz = pz + dz;
  ob[j * 3] = ox; ob[j * 3 + 1] = oy; ob[j * 3 + 2] = oz;
}

__global__ __launch_bounds__(1024) void fk_main(const float* __restrict__ pred,
                                                const float* __restrict__ offs,
                                                const float* __restrict__ agg,
                                                float* __restrict__ out) {
  int x = threadIdx.x;            // lane = t offset within quarter
  int y = threadIdx.y;            // chain 0..3 (wave-uniform)
  int z = threadIdx.z;            // quarter 0..3 (wave-uniform)
  int b = blockIdx.x;

  __shared__ float sagg1[4][12];
  __shared__ float sagg2[4][12];
  __shared__ float ebuf[12];
  __shared__ float sg[P1B][13];   // block-local prefix f per t (stride-13)
  __shared__ float s9[P1B][13];   // (r9, p9) handoff chain2 -> forks

  int tl = z * 64 + x;            // t offset in this block's 256
  int t = b * P1B + tl;
  int s = x + 64 * y;             // scan index 0..255 within the z-group
  const float* q = pred + (size_t)t * ROW;
  float* ob = out + (size_t)t * 66;

  // ---- phase A: z=0 local scan, z=1 aggregate scan (R9-validated) ----
  Aff v, v2;
  if (z == 0) {
    elem_transform(pred, b * P1B + s, v);     // L2-hot after K1
    wave_scan(v, x);
    if (x == 63) {
#pragma unroll
      for (int k = 0; k < 9; ++k) sagg1[y][k] = v.A[k];
#pragma unroll
      for (int k = 0; k < 3; ++k) sagg1[y][9 + k] = v.b[k];
    }
  } else if (z == 1) {
    const float4* a = (const float4*)(agg + (size_t)s * 12);
    float4 a0 = a[0], a1 = a[1], a2 = a[2];
    v2.A[0] = a0.x; v2.A[1] = a0.y; v2.A[2] = a0.z; v2.A[3] = a0.w;
    v2.A[4] = a1.x; v2.A[5] = a1.y; v2.A[6] = a1.z; v2.A[7] = a1.w;
    v2.A[8] = a2.x; v2.b[0] = a2.y; v2.b[1] = a2.z; v2.b[2] = a2.w;
    wave_scan(v2, x);
    if (x == 63) {
#pragma unroll
      for (int k = 0; k < 9; ++k) sagg2[y][k] = v2.A[k];
#pragma unroll
      for (int k = 0; k < 3; ++k) sagg2[y][9 + k] = v2.b[k];
    }
  }
  __syncthreads();                               // barrier #1

  if (z == 0) {
    Aff pre; aff_identity(pre);
    for (int w = 0; w < y; ++w) {
      Aff gg, t2;
#pragma unroll
      for (int k = 0; k < 9; ++k) gg.A[k] = sagg1[w][k];
#pragma unroll
      for (int k = 0; k < 3; ++k) gg.b[k] = sagg1[w][9 + k];
      compose(pre, gg, t2); pre = t2;
    }
    Aff f; compose(pre, v, f);     // block-local inclusive prefix for t_s
#pragma unroll
    for (int k = 0; k < 9; ++k) sg[s][k] = f.A[k];
#pragma unroll
    for (int k = 0; k < 3; ++k) sg[s][9 + k] = f.b[k];
  } else if (z == 1 && b > 0 && s == b - 1) {
    Aff pre; aff_identity(pre);
    for (int w = 0; w < y; ++w) {
      Aff gg, t2;
#pragma unroll
      for (int k = 0; k < 9; ++k) gg.A[k] = sagg2[w][k];
#pragma unroll
      for (int k = 0; k < 3; ++k) gg.b[k] = sagg2[w][9 + k];
      compose(pre, gg, t2); pre = t2;
    }
    Aff incl; compose(pre, v2, incl);   // inclusive agg scan at s = b-1
#pragma unroll
    for (int k = 0; k < 9; ++k) ebuf[k] = incl.A[k];
#pragma unroll
    for (int k = 0; k < 3; ++k) ebuf[9 + k] = incl.b[k];
  }
  __syncthreads();                               // barrier #2

  // ---- per-thread global prefix g = eb ∘ f(tl) ----
  Aff eb;
  if (b == 0) aff_identity(eb);
  else {
#pragma unroll
    for (int k = 0; k < 9; ++k) eb.A[k] = ebuf[k];
#pragma unroll
    for (int k = 0; k < 3; ++k) eb.b[k] = ebuf[9 + k];
  }
  Aff fl;
#pragma unroll
  for (int k = 0; k < 9; ++k) fl.A[k] = sg[tl][k];
#pragma unroll
  for (int k = 0; k < 3; ++k) fl.b[k] = sg[tl][9 + k];
  Aff g; compose(eb, fl, g);
  const float* R = g.A;
  float px = g.b[0], py = g.b[1], pz = g.b[2];

  // ---- phase B part 1 (loads on demand; <=3 live rows per thread) ----
  float M[9], ra[9], rb[9];
  if (y == 0) {                    // {0,1,4,7,10}
    ob[0] = px; ob[1] = py; ob[2] = pz;
    float p1x, p1y, p1z, p4x, p4y, p4z, p7x, p7y, p7z, dx, dy, dz;
    childp(R, offs, 1, px, py, pz, p1x, p1y, p1z, ob);     // rots[1] = R
    childp(R, offs, 4, p1x, p1y, p1z, p4x, p4y, p4z, ob);  // parent 1, rot R
    Rowv w = loadrow(q, 4); rowmat(w, M); mat_mul(R, M, ra);      // r4
    childp(ra, offs, 7, p4x, p4y, p4z, p7x, p7y, p7z, ob);
    w = loadrow(q, 7); rowmat(w, M); mat_mul(ra, M, rb);          // r7
    childp(rb, offs, 10, p7x, p7y, p7z, dx, dy, dz, ob);
  } else if (y == 1) {             // {2,5,8,11}
    float p2x, p2y, p2z, p5x, p5y, p5z, p8x, p8y, p8z, dx, dy, dz;
    childp(R, offs, 2, px, py, pz, p2x, p2y, p2z, ob);
    Rowv w = loadrow(q, 2); rowmat(w, M); mat_mul(R, M, ra);      // r2
    childp(ra, offs, 5, p2x, p2y, p2z, p5x, p5y, p5z, ob);
    w = loadrow(q, 5); rowmat(w, M); mat_mul(ra, M, rb);          // r5
    childp(rb, offs, 8, p5x, p5y, p5z, p8x, p8y, p8z, ob);
    w = loadrow(q, 8); rowmat(w, M); mat_mul(rb, M, ra);          // r8
    childp(ra, offs, 11, p8x, p8y, p8z, dx, dy, dz, ob);
  } else if (y == 2) {             // {3,6,9,12,15} + publish (r9,p9)
    float p3x, p3y, p3z, p6x, p6y, p6z, p9x, p9y, p9z;
    float p12x, p12y, p12z, dx, dy, dz;
    childp(R, offs, 3, px, py, pz, p3x, p3y, p3z, ob);
    Rowv w = loadrow(q, 3); rowmat(w, M); mat_mul(R, M, ra);      // r3
    childp(ra, offs, 6, p3x, p3y, p3z, p6x, p6y, p6z, ob);
    w = loadrow(q, 6); rowmat(w, M); mat_mul(ra, M, rb);          // r6
    childp(rb, offs, 9, p6x, p6y, p6z, p9x, p9y, p9z, ob);
    w = loadrow(q, 9); rowmat(w, M); mat_mul(rb, M, ra);          // r9
#pragma unroll
    for (int k = 0; k < 9; ++k) s9[tl][k] = ra[k];
    s9[tl][9] = p9x; s9[tl][10] = p9y; s9[tl][11] = p9z;
    childp(ra, offs, 12, p9x, p9y, p9z, p12x, p12y, p12z, ob);
    w = loadrow(q, 12); rowmat(w, M); mat_mul(ra, M, rb);         // r12
    childp(rb, offs, 15, p12x, p12y, p12z, dx, dy, dz, ob);
  }
  __syncthreads();                               // barrier #3 (r9 ready)

  // ---- phase B part 2: forks off joint 9 ----
  if (y == 0 || y == 3) {
    float r9s[9];
#pragma unroll
    for (int k = 0; k < 9; ++k) r9s[k] = s9[tl][k];
    float p9x = s9[tl][9], p9y = s9[tl][10], p9z = s9[tl][11];
    int jA, jB, jC, jD;
    if (y == 3) { jA = 13; jB = 16; jC = 18; jD = 20; }   // fork A
    else        { jA = 14; jB = 17; jC = 19; jD = 21; }   // fork B
    float pAx, pAy, pAz, pBx, pBy, pBz, pCx, pCy, pCz, dx, dy, dz;
    childp(r9s, offs, jA, p9x, p9y, p9z, pAx, pAy, pAz, ob);
    Rowv w = loadrow(q, jA); rowmat(w, M); mat_mul(r9s, M, rb);   // rA
    childp(rb, offs, jB, pAx, pAy, pAz, pBx, pBy, pBz, ob);
    w = loadrow(q, jB); rowmat(w, M); mat_mul(rb, M, ra);         // rB
    childp(ra, offs, jC, pBx, pBy, pBz, pCx, pCy, pCz, ob);
    w = loadrow(q, jC); rowmat(w, M); mat_mul(ra, M, rb);         // rC
    childp(rb, offs, jD, pCx, pCy, pCz, dx, dy, dz, ob);
  }
}

extern "C" void kernel_launch(void* const* d_in, const int* in_sizes, int n_in,
                              void* d_out, int out_size, void* d_ws, size_t ws_size,
                              hipStream_t stream) {
  const float* pred = (const float*)d_in[0];   // (L, 22, 6) fp32
  const float* offs = (const float*)d_in[1];   // (22, 3)    fp32
  float* out = (float*)d_out;                  // (L, 22, 3) fp32
  float* agg = (float*)d_ws;                   // 12 * NSCB floats

  fk_agg<<<NSCB, P1B, 0, stream>>>(pred, agg);
  fk_main<<<NSCB, dim3(64, 4, 4), 0, stream>>>(pred, offs, agg, out);
}